// Round 7
// baseline (364.708 us; speedup 1.0000x reference)
//
#include <hip/hip_runtime.h>
#include <hip/hip_fp16.h>

// CTC-like forward scan. R18 = R14 scan body, 8 INDEPENDENT batch-waves/block.
//   G_t[p] = G_{t-1}[p] + W_t[p] * G_{t-1}[p-1],  W = exp(x_i - x_4)
// Evidence trail: three different staging schemes (compiler at-use ds_read
// R14=186us, asm-burst->scratch R15=188us, named-asm->spill R17=191us) tie =>
// staging latency is NOT the binder. VALUBusy 4.6 of a 6.25 single-wave
// ceiling => wave issues ~74% of cycles; busy-cy/step ~80 vs ~19 static VALU
// => either a ~4cy/instr single-wave issue cap or ~2x hidden instrs.
// Discriminating experiment: TWO waves per SIMD. 512-thread blocks, wave w
// handles batch blockIdx.x*8+w fully independently: own ring section, own
// garr, own per-wave vmcnt staging pipeline, ZERO main-loop barriers. Any
// even wave->SIMD distribution yields 2 waves/SIMD -> issue slots interleave.
// Cap-model predicts ~1.4x; fat-model predicts neutral. Either outcome
// resolves the model.
// Numerics identical to R14/R17 (passed, absmax <= 2e-3): f16 weights via
// v_perm + forced v_fma_mix_f32, renorm every 8 steps, down-only alignment,
// boundary via one v_mov_dpp wave_shr:1, logs = sum x4 in f32, log2 epilogue.

#define TT 4096
#define BB 64
#define PP 512
#define LN2F 0.69314718055994531f

typedef unsigned u32x4 __attribute__((ext_vector_type(4)));

__device__ __forceinline__ unsigned f16_bits(float f) {
    return (unsigned)__half_as_ushort(__float2half(f));   // v_cvt_f16_f32, RNE
}

// prepass: x[t][b][5] -> xq[b*4096+t] = {f16W0|W1, f16W2|W3, f32 x4, 0}
// j = b*4096+t: writes coalesced; reads strided 320B (5MB input, L2-absorbed).
__global__ __launch_bounds__(256, 1)
void ctc_prepass(const float* __restrict__ x, u32x4* __restrict__ xq) {
    int j = blockIdx.x * 256 + threadIdx.x;
    int b = j >> 12, t = j & 4095;
    const float* r = x + (size_t)(t * 64 + b) * 5;
    float x0 = r[0], x1 = r[1], x2 = r[2], x3 = r[3], x4 = r[4];
    float w0 = fminf(__expf(x0 - x4), 65000.0f);   // clamp: f16 inf insurance
    float w1 = fminf(__expf(x1 - x4), 65000.0f);
    float w2 = fminf(__expf(x2 - x4), 65000.0f);
    float w3 = fminf(__expf(x3 - x4), 65000.0f);
    u32x4 o;
    o[0] = f16_bits(w0) | (f16_bits(w1) << 16);
    o[1] = f16_bits(w2) | (f16_bits(w3) << 16);
    o[2] = __float_as_uint(x4);
    o[3] = 0u;
    xq[j] = o;
}

__device__ __forceinline__ void gload_lds16(const void* g, void* l) {
    auto gp = (const __attribute__((address_space(1))) void*)(uintptr_t)g;
    auto lp = (__attribute__((address_space(3))) void*)(uintptr_t)l;
    __builtin_amdgcn_global_load_lds(gp, lp, 16, 0, 0);
}

// lane n <- lane n-1 across the whole wave; lane 0 keeps old (overridden).
__device__ __forceinline__ int shl1w_i(int s) {
    return __builtin_amdgcn_update_dpp(s, s, 0x138 /*wave_shr:1*/, 0xF, 0xF, false);
}
__device__ __forceinline__ float shl1w_f(float s) {
    return __int_as_float(shl1w_i(__float_as_int(s)));
}

// acc += s * f16(lo/hi of p)   -- one v_fma_mix_f32, f16 source in S1
#define FMA_MIX_LO(acc, s, p)                                              \
    asm("v_fma_mix_f32 %0, %1, %2, %0 op_sel:[0,0,0] op_sel_hi:[0,1,0]"    \
        : "+v"(acc) : "v"(s), "v"(p))
#define FMA_MIX_HI(acc, s, p)                                              \
    asm("v_fma_mix_f32 %0, %1, %2, %0 op_sel:[0,1,0] op_sel_hi:[0,1,0]"    \
        : "+v"(acc) : "v"(s), "v"(p))

__global__ __launch_bounds__(512, 1)
void ctc_scan(const u32x4* __restrict__ xq, const int* __restrict__ seqs,
              const int* __restrict__ seqlens, float* __restrict__ out) {
    // per-wave private sections: 8 x (8KB ring + 513-f32 garr) ~ 82KB
    __shared__ __align__(16) u32x4 ring[8][512];   // 8 chunks x 64 rows each
    __shared__ float garr[8][PP + 1];

    const int tid = threadIdx.x;
    const int w = tid >> 6;                        // wave 0..7 = its own batch
    const int l = tid & 63;                        // lane
    const int b = blockIdx.x * 8 + w;              // batch index
    const bool lane0 = (l == 0);

    // per-lane v_perm byte controls (value i at bytes 2i,2i+1 of {row[1]:row[0]})
    unsigned ctrl[4];
#pragma unroll
    for (int k = 0; k < 4; ++k) {
        unsigned i0 = (unsigned)seqs[b * PP + 8 * l + 2 * k];
        unsigned i1 = (unsigned)seqs[b * PP + 8 * l + 2 * k + 1];
        ctrl[k] = (2 * i0) | ((2 * i0 + 1) << 8) | ((2 * i1) << 16) | ((2 * i1 + 1) << 24);
    }

    // column-major: row t of batch b at xq[b*4096 + t]; coalesced staging.
    const u32x4* gsrc = xq + (size_t)b * 4096;

    // ---- stage chunks 0..3 into this wave's ring (per-wave vmcnt pipeline) ----
#pragma unroll
    for (int c0 = 0; c0 < 4; ++c0)
        gload_lds16(gsrc + c0 * 64 + l, &ring[w][c0 * 64 + l]);
    asm volatile("s_waitcnt vmcnt(3)" ::: "memory");   // chunk 0 resident

    float F[8];                                    // G values, frame 2^M
#pragma unroll
    for (int i = 0; i < 8; ++i) F[i] = 0.0f;
    int M = 0;
    float logs = 0.0f;                             // sum of x_4

    u32x4 wA[8], wB[8];
#pragma unroll
    for (int i = 0; i < 8; ++i) wA[i] = ring[w][i];   // window 0
    int nrow = 8;                                  // ring row of next window

    auto window = [&](u32x4 (&cur)[8], u32x4 (&nxt)[8]) {
        // ---- load next window (compiler-managed; staging scheme is perf-
        //      neutral per R14/R15/R17 triple-tie) ----
        const int rb = nrow & 511;
        nrow += 8;
#pragma unroll
        for (int i = 0; i < 8; ++i) nxt[i] = ring[w][rb + i];
        asm volatile("" ::: "memory");

        // ---- window bookkeeping: renorm + neighbor frame alignment ----
        float m = F[0];
#pragma unroll
        for (int i = 1; i < 8; ++i) m = fmaxf(m, F[i]);
        int e2 = ((__float_as_int(m) >> 23) & 0xFF) - 127;
        e2 = (m > 0.0f) ? e2 : 0;
        const int Mp = M + e2;                     // post-renorm frame
        const int Mlp = shl1w_i(Mp);               // neighbor's post-renorm frame
        int dl = (lane0 ? 0 : Mlp) - Mp;           // lane0 left nbr: G[0]=1, frame 0
        int dlc = dl > 0 ? dl : 0;                 // down-only self-squash
        const int Mnew = Mp + dlc;
        const int sh = Mnew - M;                   // >= 0
#pragma unroll
        for (int i = 0; i < 8; ++i) F[i] = ldexpf(F[i], -sh);
        M = Mnew;
        int dn = Mlp - M; dn = dn > 0 ? 0 : dn;
        const float sA   = ldexpf(1.0f, dn);       // neighbor -> my frame
        const float sAx  = lane0 ? 0.0f : sA;
        const float cfin = lane0 ? ldexpf(1.0f, -M) : 0.0f;  // G[0]=1 in my frame

        // ---- 8 steps: F[i] += Fs[i] * W[i]  (forced v_fma_mix_f32) ----
#pragma unroll
        for (int u = 0; u < 8; ++u) {
            const u32x4 row = cur[u];
            logs += __uint_as_float(row[2]);
            unsigned p0 = __builtin_amdgcn_perm(row[1], row[0], ctrl[0]);
            unsigned p1 = __builtin_amdgcn_perm(row[1], row[0], ctrl[1]);
            unsigned p2 = __builtin_amdgcn_perm(row[1], row[0], ctrl[2]);
            unsigned p3 = __builtin_amdgcn_perm(row[1], row[0], ctrl[3]);

            const float Flr = shl1w_f(F[7]);       // 1 DPP: lane n <- n-1
            const float fin = fmaf(Flr, sAx, cfin);

            FMA_MIX_HI(F[7], F[6], p3);            // F[7] += F[6] * W7
            FMA_MIX_LO(F[6], F[5], p3);
            FMA_MIX_HI(F[5], F[4], p2);
            FMA_MIX_LO(F[4], F[3], p2);
            FMA_MIX_HI(F[3], F[2], p1);
            FMA_MIX_LO(F[2], F[1], p1);
            FMA_MIX_HI(F[1], F[0], p0);
            FMA_MIX_LO(F[0], fin,  p0);
        }
    };

#pragma unroll 1
    for (int c = 0; c < 64; ++c) {
        int cs = (c + 4 > 63) ? 63 : (c + 4);
        gload_lds16(gsrc + cs * 64 + l, &ring[w][((c + 4) & 7) * 64 + l]);
        asm volatile("s_waitcnt vmcnt(3)" ::: "memory");   // chunk c+1 resident

#pragma unroll 1
        for (int pr = 0; pr < 4; ++pr) {
            window(wA, wB);
            window(wB, wA);
        }
    }

    // ---- epilogue: log2 reconstruction (denormal-safe), per-wave ----
    const float lgS = logs * 1.44269504088896341f;  // log2(prod S)
#pragma unroll
    for (int i = 0; i < 8; ++i) {
        float v = fmaxf(F[i] * 16777216.0f, 1e-38f);
        garr[w][8 * l + 1 + i] = __log2f(v) - 24.0f + (float)M + lgS;
    }
    if (lane0) garr[w][0] = lgS;                    // position 0: log2(1) + lgS
    __syncthreads();                                // cheap, once; all waves done
    if (lane0) {
        const int sl = seqlens[b];
        out[b] = -(garr[w][sl] * LN2F) / (float)TT;
    }
}

extern "C" void kernel_launch(void* const* d_in, const int* in_sizes, int n_in,
                              void* d_out, int out_size, void* d_ws, size_t ws_size,
                              hipStream_t stream) {
    const float* x       = (const float*)d_in[0];
    const int*   seqs    = (const int*)d_in[1];
    const int*   seqlens = (const int*)d_in[2];
    float*       out     = (float*)d_out;
    u32x4*       xq      = (u32x4*)d_ws;           // TT*BB rows x 16 B = 4 MB

    ctc_prepass<<<(TT * BB) / 256, 256, 0, stream>>>(x, xq);
    ctc_scan<<<BB / 8, 512, 0, stream>>>(xq, seqs, seqlens, out);
}

// Round 8
// 164.000 us; speedup vs baseline: 2.2238x; 2.2238x over previous
//
#include <hip/hip_runtime.h>
#include <hip/hip_fp16.h>

// CTC-like forward scan. R19 = meet-in-the-middle: fwd wave x bwd wave.
//   out = e_sl^T B_T...B_1 e_0,  B_t lower-bidiagonal (diag S_t, sub V_t).
// R18 resolved the model: ~40 real VALU instrs/step x 2cy (2 waves/SIMD ->
// 88% SIMD-busy for only 1.22x aggregate) => VALU-throughput-bound per wave.
// Algorithmic 2x: fwd wave computes u = B_{T/2}..B_1 e_0 (2048 steps,
// verified R14 code); bwd wave computes w^T = e_sl^T B_T..B_{T/2+1} via the
// mirror recurrence gb[p] += W_t[p+1]*gb[p+1] (same G-space trick, SAME
// v_perm ctrls since W[p+1] uses seqs[p], DPP wave_shl:1, constant inflow
// at position 512 = [sl==512], lane63 squashes to frame 0 only when sl==512).
// Junction: out = sum_p gf[p] gb[p] 2^(Mf+Mb) x prod(S) -> 513-entry LSE
// epilogue. Waves fully independent (own rings/vmcnt, zero main-loop
// barriers, different SIMDs); junction via one __syncthreads.
// Numerics per-wave identical to R14 (absmax <= 2e-3): f16 W via v_perm +
// forced v_fma_mix_f32, renorm every 8 steps, down-only alignment.

#define TT 4096
#define BB 64
#define PP 512
#define LN2F 0.69314718055994531f
#define LOG2E 1.44269504088896341f

typedef unsigned u32x4 __attribute__((ext_vector_type(4)));

__device__ __forceinline__ unsigned f16_bits(float f) {
    return (unsigned)__half_as_ushort(__float2half(f));   // v_cvt_f16_f32, RNE
}

// prepass: x[t][b][5] -> xq[b*4096+t] = {f16W0|W1, f16W2|W3, f32 x4, 0}
__global__ __launch_bounds__(256, 1)
void ctc_prepass(const float* __restrict__ x, u32x4* __restrict__ xq) {
    int j = blockIdx.x * 256 + threadIdx.x;
    int b = j >> 12, t = j & 4095;
    const float* r = x + (size_t)(t * 64 + b) * 5;
    float x0 = r[0], x1 = r[1], x2 = r[2], x3 = r[3], x4 = r[4];
    float w0 = fminf(__expf(x0 - x4), 65000.0f);   // clamp: f16 inf insurance
    float w1 = fminf(__expf(x1 - x4), 65000.0f);
    float w2 = fminf(__expf(x2 - x4), 65000.0f);
    float w3 = fminf(__expf(x3 - x4), 65000.0f);
    u32x4 o;
    o[0] = f16_bits(w0) | (f16_bits(w1) << 16);
    o[1] = f16_bits(w2) | (f16_bits(w3) << 16);
    o[2] = __float_as_uint(x4);
    o[3] = 0u;
    xq[j] = o;
}

__device__ __forceinline__ void gload_lds16(const void* g, void* l) {
    auto gp = (const __attribute__((address_space(1))) void*)(uintptr_t)g;
    auto lp = (__attribute__((address_space(3))) void*)(uintptr_t)l;
    __builtin_amdgcn_global_load_lds(gp, lp, 16, 0, 0);
}

// lane n <- lane n-1 (wave_shr:1); lane 0 keeps old (overridden).
__device__ __forceinline__ int shl1w_i(int s) {
    return __builtin_amdgcn_update_dpp(s, s, 0x138, 0xF, 0xF, false);
}
__device__ __forceinline__ float shl1w_f(float s) {
    return __int_as_float(shl1w_i(__float_as_int(s)));
}
// lane n <- lane n+1 (wave_shl:1); lane 63 keeps old (overridden).
__device__ __forceinline__ int sh1up_i(int s) {
    return __builtin_amdgcn_update_dpp(s, s, 0x130, 0xF, 0xF, false);
}
__device__ __forceinline__ float sh1up_f(float s) {
    return __int_as_float(sh1up_i(__float_as_int(s)));
}

// acc += s * f16(lo/hi of p)   -- one v_fma_mix_f32, f16 source in S1
#define FMA_MIX_LO(acc, s, p)                                              \
    asm("v_fma_mix_f32 %0, %1, %2, %0 op_sel:[0,0,0] op_sel_hi:[0,1,0]"    \
        : "+v"(acc) : "v"(s), "v"(p))
#define FMA_MIX_HI(acc, s, p)                                              \
    asm("v_fma_mix_f32 %0, %1, %2, %0 op_sel:[0,1,0] op_sel_hi:[0,1,0]"    \
        : "+v"(acc) : "v"(s), "v"(p))

__global__ __launch_bounds__(128, 1)
void ctc_scan(const u32x4* __restrict__ xq, const int* __restrict__ seqs,
              const int* __restrict__ seqlens, float* __restrict__ out) {
    __shared__ __align__(16) u32x4 ringF[512];     // 8 KB each
    __shared__ __align__(16) u32x4 ringB[512];
    __shared__ float garrF[PP + 1];
    __shared__ float garrB[PP + 1];
    __shared__ float lgSh[2];

    const int tid = threadIdx.x;
    const int w = tid >> 6;                        // 0 = fwd, 1 = bwd
    const int l = tid & 63;
    const int b = blockIdx.x;
    const bool lane0 = (l == 0);
    const bool lane63 = (l == 63);

    // per-lane v_perm byte controls -- IDENTICAL for fwd and bwd:
    // fwd lane l owns G[8l+1..8l+8] (W[8l+1+i] uses seqs[8l+i]);
    // bwd lane l owns gb[8l..8l+7]  (W[8l+k+1] uses seqs[8l+k]).
    unsigned ctrl[4];
#pragma unroll
    for (int k = 0; k < 4; ++k) {
        unsigned i0 = (unsigned)seqs[b * PP + 8 * l + 2 * k];
        unsigned i1 = (unsigned)seqs[b * PP + 8 * l + 2 * k + 1];
        ctrl[k] = (2 * i0) | ((2 * i0 + 1) << 8) | ((2 * i1) << 16) | ((2 * i1 + 1) << 24);
    }

    const u32x4* gsrc = xq + (size_t)b * 4096;     // row t at gsrc[t]

    float F[8];
    int M = 0;
    float logs = 0.0f;

    if (w == 0) {
        // ================= FORWARD: rows 0..2047 (verified R14 body) ======
#pragma unroll
        for (int i = 0; i < 8; ++i) F[i] = 0.0f;
#pragma unroll
        for (int c0 = 0; c0 < 4; ++c0)
            gload_lds16(gsrc + c0 * 64 + l, &ringF[c0 * 64 + l]);
        asm volatile("s_waitcnt vmcnt(3)" ::: "memory");

        u32x4 wA[8], wB[8];
#pragma unroll
        for (int i = 0; i < 8; ++i) wA[i] = ringF[i];
        int nrow = 8;

        auto fwin = [&](u32x4 (&cur)[8], u32x4 (&nxt)[8]) {
            const int rb = nrow & 511;
            nrow += 8;
#pragma unroll
            for (int i = 0; i < 8; ++i) nxt[i] = ringF[rb + i];
            asm volatile("" ::: "memory");

            float m = F[0];
#pragma unroll
            for (int i = 1; i < 8; ++i) m = fmaxf(m, F[i]);
            int e2 = ((__float_as_int(m) >> 23) & 0xFF) - 127;
            e2 = (m > 0.0f) ? e2 : 0;
            const int Mp = M + e2;
            const int Mlp = shl1w_i(Mp);
            int dl = (lane0 ? 0 : Mlp) - Mp;
            int dlc = dl > 0 ? dl : 0;
            const int Mnew = Mp + dlc;
            const int sh = Mnew - M;
#pragma unroll
            for (int i = 0; i < 8; ++i) F[i] = ldexpf(F[i], -sh);
            M = Mnew;
            int dn = Mlp - M; dn = dn > 0 ? 0 : dn;
            const float sAx  = lane0 ? 0.0f : ldexpf(1.0f, dn);
            const float cfin = lane0 ? ldexpf(1.0f, -M) : 0.0f;

#pragma unroll
            for (int u = 0; u < 8; ++u) {
                const u32x4 row = cur[u];
                logs += __uint_as_float(row[2]);
                unsigned p0 = __builtin_amdgcn_perm(row[1], row[0], ctrl[0]);
                unsigned p1 = __builtin_amdgcn_perm(row[1], row[0], ctrl[1]);
                unsigned p2 = __builtin_amdgcn_perm(row[1], row[0], ctrl[2]);
                unsigned p3 = __builtin_amdgcn_perm(row[1], row[0], ctrl[3]);
                const float Flr = shl1w_f(F[7]);
                const float fin = fmaf(Flr, sAx, cfin);
                FMA_MIX_HI(F[7], F[6], p3);
                FMA_MIX_LO(F[6], F[5], p3);
                FMA_MIX_HI(F[5], F[4], p2);
                FMA_MIX_LO(F[4], F[3], p2);
                FMA_MIX_HI(F[3], F[2], p1);
                FMA_MIX_LO(F[2], F[1], p1);
                FMA_MIX_HI(F[1], F[0], p0);
                FMA_MIX_LO(F[0], fin,  p0);
            }
        };

#pragma unroll 1
        for (int c = 0; c < 32; ++c) {
            int cs = (c + 4 > 31) ? 31 : (c + 4);
            gload_lds16(gsrc + cs * 64 + l, &ringF[((c + 4) & 7) * 64 + l]);
            asm volatile("s_waitcnt vmcnt(3)" ::: "memory");
#pragma unroll 1
            for (int pr = 0; pr < 4; ++pr) { fwin(wA, wB); fwin(wB, wA); }
        }

        // junction write: garrF[p] = log2(gf[p]) + Mf ; garrF[0] = 0 (G[0]=1)
#pragma unroll
        for (int i = 0; i < 8; ++i) {
            float v = fmaxf(F[i] * 16777216.0f, 1e-38f);
            garrF[8 * l + 1 + i] = __log2f(v) - 24.0f + (float)M;
        }
        if (lane0) { garrF[0] = 0.0f; lgSh[0] = logs * LOG2E; }
    } else {
        // ================= BACKWARD: rows 4095..2048 (mirror) =============
        const int sl = seqlens[b];
        const bool b512 = (sl == PP);
#pragma unroll
        for (int k = 0; k < 8; ++k) F[k] = (8 * l + k == sl) ? 1.0f : 0.0f;
#pragma unroll
        for (int c0 = 0; c0 < 4; ++c0) {
            const int cp = 63 - c0;
            gload_lds16(gsrc + cp * 64 + l, &ringB[(cp & 7) * 64 + l]);
        }
        asm volatile("s_waitcnt vmcnt(3)" ::: "memory");   // chunk 63 resident

        u32x4 wA[8], wB[8];
#pragma unroll
        for (int i = 0; i < 8; ++i) wA[i] = ringB[511 - i];  // rows 4095..4088
        int nbase = 4095 - 8;                       // top row of next window

        auto bwin = [&](u32x4 (&cur)[8], u32x4 (&nxt)[8]) {
            const int rb = nbase & 511;
            nbase -= 8;
#pragma unroll
            for (int i = 0; i < 8; ++i) nxt[i] = ringB[(rb - i) & 511];
            asm volatile("" ::: "memory");

            float m = F[0];
#pragma unroll
            for (int i = 1; i < 8; ++i) m = fmaxf(m, F[i]);
            int e2 = ((__float_as_int(m) >> 23) & 0xFF) - 127;
            e2 = (m > 0.0f) ? e2 : 0;
            const int Mp = M + e2;
            const int Mup = sh1up_i(Mp);            // lane l+1's frame
            // lane63's right neighbor: constant [sl==512] at frame 0 (only
            // squash when it's actually nonzero)
            int nb = lane63 ? (b512 ? 0 : -1048576) : Mup;
            int dl = nb - Mp;
            int dlc = dl > 0 ? dl : 0;
            const int Mnew = Mp + dlc;
            const int sh = Mnew - M;
#pragma unroll
            for (int i = 0; i < 8; ++i) F[i] = ldexpf(F[i], -sh);
            M = Mnew;
            int dn = Mup - M; dn = dn > 0 ? 0 : dn;
            const float sAx  = lane63 ? 0.0f : ldexpf(1.0f, dn);
            const float cfin = (lane63 && b512) ? ldexpf(1.0f, -M) : 0.0f;

#pragma unroll
            for (int u = 0; u < 8; ++u) {
                const u32x4 row = cur[u];
                logs += __uint_as_float(row[2]);
                unsigned p0 = __builtin_amdgcn_perm(row[1], row[0], ctrl[0]);
                unsigned p1 = __builtin_amdgcn_perm(row[1], row[0], ctrl[1]);
                unsigned p2 = __builtin_amdgcn_perm(row[1], row[0], ctrl[2]);
                unsigned p3 = __builtin_amdgcn_perm(row[1], row[0], ctrl[3]);
                const float Bur = sh1up_f(F[0]);    // lane n <- n+1's gb-bottom
                const float fin = fmaf(Bur, sAx, cfin);
                // gb[p] += W[p+1]*gb[p+1], ascending (old upper values)
                FMA_MIX_LO(F[0], F[1], p0);
                FMA_MIX_HI(F[1], F[2], p0);
                FMA_MIX_LO(F[2], F[3], p1);
                FMA_MIX_HI(F[3], F[4], p1);
                FMA_MIX_LO(F[4], F[5], p2);
                FMA_MIX_HI(F[5], F[6], p2);
                FMA_MIX_LO(F[6], F[7], p3);
                FMA_MIX_HI(F[7], fin,  p3);
            }
        };

#pragma unroll 1
        for (int c = 0; c < 32; ++c) {
            int cp = 59 - c; cp = cp < 32 ? 32 : cp;
            gload_lds16(gsrc + cp * 64 + l, &ringB[(cp & 7) * 64 + l]);
            asm volatile("s_waitcnt vmcnt(3)" ::: "memory");
#pragma unroll 1
            for (int pr = 0; pr < 4; ++pr) { bwin(wA, wB); bwin(wB, wA); }
        }

        // junction write: garrB[p] = log2(gb[p]) + Mb ; garrB[512] = [sl==512]
#pragma unroll
        for (int k = 0; k < 8; ++k) {
            float v = fmaxf(F[k] * 16777216.0f, 1e-38f);
            garrB[8 * l + k] = __log2f(v) - 24.0f + (float)M;
        }
        if (lane0) { garrB[PP] = b512 ? 0.0f : -1e30f; lgSh[1] = logs * LOG2E; }
    }

    __syncthreads();

    // ---- junction: log2(out) = LSE2_p(garrF[p]+garrB[p]) + lgSF + lgSB ----
    if (w == 0) {
        float smax = -3.0e38f;
#pragma unroll
        for (int k = 0; k < 9; ++k) {
            const int p = l + (k << 6);
            if (p <= PP) smax = fmaxf(smax, garrF[p] + garrB[p]);
        }
#pragma unroll
        for (int off = 32; off >= 1; off >>= 1)
            smax = fmaxf(smax, __shfl_xor(smax, off));
        float ssum = 0.0f;
#pragma unroll
        for (int k = 0; k < 9; ++k) {
            const int p = l + (k << 6);
            if (p <= PP) ssum += exp2f((garrF[p] + garrB[p]) - smax);
        }
#pragma unroll
        for (int off = 32; off >= 1; off >>= 1)
            ssum += __shfl_xor(ssum, off);
        if (lane0)
            out[b] = -((smax + __log2f(ssum)) + lgSh[0] + lgSh[1]) * LN2F / (float)TT;
    }
}

extern "C" void kernel_launch(void* const* d_in, const int* in_sizes, int n_in,
                              void* d_out, int out_size, void* d_ws, size_t ws_size,
                              hipStream_t stream) {
    const float* x       = (const float*)d_in[0];
    const int*   seqs    = (const int*)d_in[1];
    const int*   seqlens = (const int*)d_in[2];
    float*       out     = (float*)d_out;
    u32x4*       xq      = (u32x4*)d_ws;           // TT*BB rows x 16 B = 4 MB

    ctc_prepass<<<(TT * BB) / 256, 256, 0, stream>>>(x, xq);
    ctc_scan<<<BB, 128, 0, stream>>>(xq, seqs, seqlens, out);
}